// Round 7
// baseline (175.779 us; speedup 1.0000x reference)
//
#include <hip/hip_runtime.h>
#include <stdint.h>

// Problem constants (B=2, S=2048 -> T=4096 tokens)
#define T_TOK   4096
#define H_DIM   1024
#define I_DIM   512
#define E_EXP   16
#define TOPK    4
#define NTILEMAX 144            // >= max total 128-row M-tiles (<=143)
#define GEMM_GRID (4 * NTILEMAX) // 576 = 8 XCD chunks of 72
#define GEMM_CHUNK (GEMM_GRID / 8)

typedef __attribute__((ext_vector_type(8))) short bf16x8;   // 8 bf16 = 4 VGPR
typedef __attribute__((ext_vector_type(4))) float f32x4;    // MFMA 16x16 acc
typedef __attribute__((ext_vector_type(8))) unsigned short ushort8;

__device__ __forceinline__ unsigned short f2bf(float f) {
  unsigned u = __float_as_uint(f);
  u = u + 0x7fffu + ((u >> 16) & 1u);          // RNE
  return (unsigned short)(u >> 16);
}
__device__ __forceinline__ float bf2f(unsigned short s) {
  return __uint_as_float(((unsigned)s) << 16);
}

__device__ __forceinline__ void gload_lds16(const void* g, void* l) {
  __builtin_amdgcn_global_load_lds(
      (const __attribute__((address_space(1))) unsigned int*)g,
      (__attribute__((address_space(3))) unsigned int*)l, 16, 0, 0);
}

// ---------------------------------------------------------------- convert
// 32B/lane/iter: 2x float4 in, 1x ushort8 out (m13 copy pattern).
__device__ __forceinline__ void cvt_seg8(const float* __restrict__ src,
                                         unsigned short* __restrict__ dst,
                                         int n8, int tid0, int stride) {
  for (int i = tid0; i < n8; i += stride) {
    float4 v0 = ((const float4*)src)[2 * i];
    float4 v1 = ((const float4*)src)[2 * i + 1];
    ushort8 o;
    o[0] = f2bf(v0.x); o[1] = f2bf(v0.y); o[2] = f2bf(v0.z); o[3] = f2bf(v0.w);
    o[4] = f2bf(v1.x); o[5] = f2bf(v1.y); o[6] = f2bf(v1.z); o[7] = f2bf(v1.w);
    ((ushort8*)dst)[i] = o;
  }
}

__global__ __launch_bounds__(256) void cvt_all_kernel(
    const float* __restrict__ x,  unsigned short* __restrict__ xb,
    const float* __restrict__ wg, unsigned short* __restrict__ wgb,
    const float* __restrict__ wu, unsigned short* __restrict__ wub,
    const float* __restrict__ wd, unsigned short* __restrict__ wdb) {
  const int tid0 = blockIdx.x * blockDim.x + threadIdx.x;
  const int stride = gridDim.x * blockDim.x;
  cvt_seg8(x,  xb,  T_TOK * H_DIM / 8, tid0, stride);
  cvt_seg8(wg, wgb, E_EXP * I_DIM * H_DIM / 8, tid0, stride);
  cvt_seg8(wu, wub, E_EXP * I_DIM * H_DIM / 8, tid0, stride);
  cvt_seg8(wd, wdb, E_EXP * H_DIM * I_DIM / 8, tid0, stride);
}

// ---------------------------------------------------------------- router 1/4
__global__ __launch_bounds__(256) void logits_kernel(
    const float* __restrict__ x, const float* __restrict__ rw,
    float* __restrict__ logits) {
  const int t = blockIdx.x * 4 + (threadIdx.x >> 6);
  const int lane = threadIdx.x & 63;
  const float* xr = x + (size_t)t * H_DIM;

  float4 xv[4];
#pragma unroll
  for (int i = 0; i < 4; ++i) xv[i] = ((const float4*)xr)[i * 64 + lane];

#pragma unroll
  for (int g = 0; g < 4; ++g) {
    float acc[4] = {0.f, 0.f, 0.f, 0.f};
#pragma unroll
    for (int e4 = 0; e4 < 4; ++e4) {
      const float* wrow = rw + (size_t)(g * 4 + e4) * H_DIM;
#pragma unroll
      for (int i = 0; i < 4; ++i) {
        float4 wv = ((const float4*)wrow)[i * 64 + lane];
        acc[e4] = fmaf(xv[i].x, wv.x, acc[e4]);
        acc[e4] = fmaf(xv[i].y, wv.y, acc[e4]);
        acc[e4] = fmaf(xv[i].z, wv.z, acc[e4]);
        acc[e4] = fmaf(xv[i].w, wv.w, acc[e4]);
      }
    }
#pragma unroll
    for (int e4 = 0; e4 < 4; ++e4)
#pragma unroll
      for (int off = 32; off > 0; off >>= 1) acc[e4] += __shfl_down(acc[e4], off, 64);
    if (lane == 0)
      ((float4*)(logits + (size_t)t * E_EXP))[g] =
          make_float4(acc[0], acc[1], acc[2], acc[3]);
  }
}

// ---------------------------------------------------------------- router 2/4
__global__ __launch_bounds__(256) void select_kernel(
    const float* __restrict__ logits, const float* __restrict__ rb,
    int* __restrict__ tidx, float* __restrict__ tw) {
  const int t = blockIdx.x * 256 + threadIdx.x;

  float sc[E_EXP], sch[E_EXP];
#pragma unroll
  for (int e = 0; e < E_EXP; ++e) {
    sc[e] = 1.f / (1.f + expf(-logits[(size_t)t * E_EXP + e]));
    sch[e] = sc[e] + rb[e];
  }

  float gsum[4];
#pragma unroll
  for (int g = 0; g < 4; ++g) {
    float m1 = -3e38f, m2 = -3e38f;
#pragma unroll
    for (int j = 0; j < 4; ++j) {
      float v = sch[g * 4 + j];
      if (v > m1) { m2 = m1; m1 = v; } else if (v > m2) { m2 = v; }
    }
    gsum[g] = m1 + m2;
  }
  int g1 = 0;
  for (int g = 1; g < 4; ++g) if (gsum[g] > gsum[g1]) g1 = g;
  int g2 = -1;
  for (int g = 0; g < 4; ++g)
    if (g != g1 && (g2 < 0 || gsum[g] > gsum[g2])) g2 = g;

  float cand[E_EXP];
#pragma unroll
  for (int e = 0; e < E_EXP; ++e)
    cand[e] = ((e >> 2) == g1 || (e >> 2) == g2) ? sch[e] : -1e9f;

  int idx[TOPK]; float wv[TOPK]; float wsum = 0.f;
#pragma unroll
  for (int k = 0; k < TOPK; ++k) {
    int bi = 0; float bv = cand[0];
#pragma unroll
    for (int e = 1; e < E_EXP; ++e) if (cand[e] > bv) { bv = cand[e]; bi = e; }
    idx[k] = bi; cand[bi] = -3e38f;
    wv[k] = sc[bi];
    wsum += wv[k];
  }
  float scale = 2.5f / (wsum + 1e-20f);
#pragma unroll
  for (int k = 0; k < TOPK; ++k) {
    tidx[t * 4 + k] = idx[k];
    tw[t * 4 + k] = wv[k] * scale;
  }
}

// ---------------------------------------------------------------- router 3/4
__global__ __launch_bounds__(256) void count_kernel(
    const int* __restrict__ tidx, int* __restrict__ counts) {
  const int e = blockIdx.x, tid = threadIdx.x;
  const int lane = tid & 63, wv = tid >> 6;
  int local = 0;
  for (int i = tid; i < T_TOK * TOPK; i += 256) local += (tidx[i] == e);
#pragma unroll
  for (int off = 32; off > 0; off >>= 1) local += __shfl_down(local, off, 64);
  __shared__ int ws[4];
  if (lane == 0) ws[wv] = local;
  __syncthreads();
  if (tid == 0) counts[e] = ws[0] + ws[1] + ws[2] + ws[3];
}

// prefix over rows AND over 128-row M-tiles (compact dispatch table)
__global__ void prefix_kernel(const int* __restrict__ counts,
                              int* __restrict__ off, int* __restrict__ toff) {
  if (threadIdx.x == 0) {
    int a = 0, tt = 0;
    for (int e = 0; e < E_EXP; ++e) {
      off[e] = a; toff[e] = tt;
      a += counts[e];
      tt += (counts[e] + 127) >> 7;
    }
    off[E_EXP] = a;                 // == 4*T
    toff[E_EXP] = tt;               // total M-tiles (<= 143)
  }
}

// ---------------------------------------------------------------- router 4/4
__global__ __launch_bounds__(256) void scatter_kernel(
    const int* __restrict__ tidx, const int* __restrict__ off,
    int* __restrict__ rowmap, int* __restrict__ rowtok) {
  const int e = blockIdx.x, tid = threadIdx.x;
  const int lane = tid & 63, wv = tid >> 6;
  __shared__ int wsum[4];
  __shared__ int srun;
  if (tid == 0) srun = 0;
  __syncthreads();
  const int base = off[e];
  for (int c = 0; c < T_TOK * TOPK / 256; ++c) {
    const int i = c * 256 + tid;
    const bool f = (tidx[i] == e);
    unsigned long long m = __ballot(f);
    int wpre = __popcll(m & ((1ull << lane) - 1ull));
    if (lane == 63) wsum[wv] = wpre + (f ? 1 : 0);
    __syncthreads();
    const int run = srun;
    int pre = 0, tot = 0;
#pragma unroll
    for (int w = 0; w < 4; ++w) {
      int v = wsum[w];
      if (w < wv) pre += v;
      tot += v;
    }
    if (f) {
      const int pos = base + run + pre + wpre;
      rowmap[i] = pos;
      rowtok[pos] = i >> 2;
    }
    __syncthreads();
    if (tid == 0) srun = run + tot;
  }
}

// decode compact tile id -> expert (monotone table walk, branchless)
__device__ __forceinline__ int find_expert(const int* __restrict__ toff, int tile) {
  int e = 0;
#pragma unroll
  for (int q = 1; q <= E_EXP; ++q) e += (toff[q] <= tile);
  return e;
}

// ---------------------------------------------------------------- gate+up GEMM
// Tile 128(M) x 128(N of I), BK=64, dual acc (gate,up). 4 waves 2x2, wave tile
// 64x64. Single-buffer 2-barrier loop, T2 swizzle, compact dispatch, XCD chunk.
__global__ __launch_bounds__(256, 2) void gateup_kernel(
    const unsigned short* __restrict__ xbf,   // [T,H]
    const unsigned short* __restrict__ wgbf,  // [E,I,H]
    const unsigned short* __restrict__ wubf,  // [E,I,H]
    const int* __restrict__ rowtok, const int* __restrict__ off,
    const int* __restrict__ toff,
    unsigned short* __restrict__ hbuf) {      // [4T,I]
  const int bid = (int)blockIdx.x;
  const int work = (bid & 7) * GEMM_CHUNK + (bid >> 3);
  const int tile = work >> 2, tn = work & 3;  // tn: 4 slices of 128 over I=512
  if (tile >= toff[E_EXP]) return;
  const int e = find_expert(toff, tile);
  const int tm = tile - toff[e];
  const int seg0 = off[e];
  const int nrows = off[e + 1] - seg0;

  __shared__ __align__(16) unsigned short As[128 * 64];  // 16KB
  __shared__ __align__(16) unsigned short Gs[128 * 64];  // 16KB
  __shared__ __align__(16) unsigned short Us[128 * 64];  // 16KB
  __shared__ int ids[128];

  const int tid = threadIdx.x;
  if (tid < 128) {
    int r = tm * 128 + tid;
    ids[tid] = rowtok[seg0 + (r < nrows ? r : 0)];       // clamp: safe read
  }
  __syncthreads();

  const int col8 = tid & 7;        // 16B chunk within a 64-elem row
  const int r0 = tid >> 3;         // row base within 32-row stripe
  const int csrc = (col8 ^ (r0 & 7)) * 8;  // pre-swizzled source column
  int tokA[4];
#pragma unroll
  for (int j = 0; j < 4; ++j) tokA[j] = ids[j * 32 + r0];

  const unsigned short* wg = wgbf + (size_t)e * I_DIM * H_DIM + (size_t)(tn * 128) * H_DIM;
  const unsigned short* wu = wubf + (size_t)e * I_DIM * H_DIM + (size_t)(tn * 128) * H_DIM;

  f32x4 accg[4][4], accu[4][4];
#pragma unroll
  for (int m = 0; m < 4; ++m)
#pragma unroll
    for (int n = 0; n < 4; ++n) { accg[m][n] = (f32x4)0.f; accu[m][n] = (f32x4)0.f; }

  const int lane = tid & 63, wid = tid >> 6;
  const int wr = wid >> 1, wc = wid & 1;
  const int frow = lane & 15, fr7 = frow & 7;
  const int kc = lane >> 4;        // base chunk (0..3) within K=64 row

  for (int kt = 0; kt < H_DIM / 64; ++kt) {
    const int kb = kt * 64 + csrc;
    __syncthreads();                         // prev compute done
#pragma unroll
    for (int j = 0; j < 4; ++j)
      gload_lds16(xbf + ((size_t)tokA[j] * H_DIM + kb), (char*)As + (j * 256 + tid) * 16);
#pragma unroll
    for (int j = 0; j < 4; ++j) {
      gload_lds16(wg + ((size_t)(j * 32 + r0) * H_DIM + kb), (char*)Gs + (j * 256 + tid) * 16);
      gload_lds16(wu + ((size_t)(j * 32 + r0) * H_DIM + kb), (char*)Us + (j * 256 + tid) * 16);
    }
    __syncthreads();                         // vmcnt(0) drained by compiler
#pragma unroll
    for (int kk = 0; kk < 2; ++kk) {
      const int swz = ((kk * 4 + kc) ^ fr7) * 8;   // swizzled elem offset
      bf16x8 af[4], bg[4], bu[4];
#pragma unroll
      for (int m = 0; m < 4; ++m)
        af[m] = *(const bf16x8*)&As[(wr * 64 + m * 16 + frow) * 64 + swz];
#pragma unroll
      for (int n = 0; n < 4; ++n) {
        bg[n] = *(const bf16x8*)&Gs[(wc * 64 + n * 16 + frow) * 64 + swz];
        bu[n] = *(const bf16x8*)&Us[(wc * 64 + n * 16 + frow) * 64 + swz];
      }
#pragma unroll
      for (int m = 0; m < 4; ++m)
#pragma unroll
        for (int n = 0; n < 4; ++n) {
          accg[m][n] = __builtin_amdgcn_mfma_f32_16x16x32_bf16(af[m], bg[n], accg[m][n], 0, 0, 0);
          accu[m][n] = __builtin_amdgcn_mfma_f32_16x16x32_bf16(af[m], bu[n], accu[m][n], 0, 0, 0);
        }
    }
  }

  // epilogue: h = silu(g)*u  (C/D layout: col=lane&15, row=(lane>>4)*4+j)
  const int lr = (lane >> 4) * 4, lc = lane & 15;
#pragma unroll
  for (int m = 0; m < 4; ++m) {
#pragma unroll
    for (int j = 0; j < 4; ++j) {
      int r = tm * 128 + wr * 64 + m * 16 + lr + j;
      if (r < nrows) {
        size_t rowoff = (size_t)(seg0 + r) * I_DIM;
#pragma unroll
        for (int n = 0; n < 4; ++n) {
          float g = accg[m][n][j];
          float u = accu[m][n][j];
          float hv = g / (1.f + __expf(-g)) * u;
          hbuf[rowoff + tn * 128 + wc * 64 + n * 16 + lc] = f2bf(hv);
        }
      }
    }
  }
}

// ---------------------------------------------------------------- down GEMM
// Tile 128(M) x 256(N of H), BK=64 over I. Wave tile 64x128.
__global__ __launch_bounds__(256, 2) void down_kernel(
    const unsigned short* __restrict__ hbuf,  // [4T,I]
    const unsigned short* __restrict__ wdbf,  // [E,H,I]
    const int* __restrict__ off, const int* __restrict__ toff,
    unsigned short* __restrict__ ybuf) {      // [4T,H]
  const int bid = (int)blockIdx.x;
  const int work = (bid & 7) * GEMM_CHUNK + (bid >> 3);
  const int tile = work >> 2, tn = work & 3;  // tn: 4 slices of 256 over H=1024
  if (tile >= toff[E_EXP]) return;
  const int e = find_expert(toff, tile);
  const int tm = tile - toff[e];
  const int seg0 = off[e];
  const int nrows = off[e + 1] - seg0;

  __shared__ __align__(16) unsigned short As[128 * 64];  // 16KB
  __shared__ __align__(16) unsigned short Bs[256 * 64];  // 32KB

  const int tid = threadIdx.x;
  const int col8 = tid & 7;
  const int r0 = tid >> 3;
  const int csrc = (col8 ^ (r0 & 7)) * 8;
  int rowA[4];
#pragma unroll
  for (int j = 0; j < 4; ++j) {
    int r = tm * 128 + j * 32 + r0;
    rowA[j] = seg0 + (r < nrows ? r : nrows - 1);
  }
  const unsigned short* wd = wdbf + (size_t)e * H_DIM * I_DIM + (size_t)(tn * 256) * I_DIM;

  f32x4 acc[4][8];
#pragma unroll
  for (int m = 0; m < 4; ++m)
#pragma unroll
    for (int n = 0; n < 8; ++n) acc[m][n] = (f32x4)0.f;

  const int lane = tid & 63, wid = tid >> 6;
  const int wr = wid >> 1, wc = wid & 1;
  const int frow = lane & 15, fr7 = frow & 7;
  const int kc = lane >> 4;

  for (int kt = 0; kt < I_DIM / 64; ++kt) {
    const int kb = kt * 64 + csrc;
    __syncthreads();
#pragma unroll
    for (int j = 0; j < 4; ++j)
      gload_lds16(hbuf + ((size_t)rowA[j] * I_DIM + kb), (char*)As + (j * 256 + tid) * 16);
#pragma unroll
    for (int j = 0; j < 8; ++j)
      gload_lds16(wd + ((size_t)(j * 32 + r0) * I_DIM + kb), (char*)Bs + (j * 256 + tid) * 16);
    __syncthreads();
#pragma unroll
    for (int kk = 0; kk < 2; ++kk) {
      const int swz = ((kk * 4 + kc) ^ fr7) * 8;
      bf16x8 af[4], bw[8];
#pragma unroll
      for (int m = 0; m < 4; ++m)
        af[m] = *(const bf16x8*)&As[(wr * 64 + m * 16 + frow) * 64 + swz];
#pragma unroll
      for (int n = 0; n < 8; ++n)
        bw[n] = *(const bf16x8*)&Bs[(wc * 128 + n * 16 + frow) * 64 + swz];
#pragma unroll
      for (int m = 0; m < 4; ++m)
#pragma unroll
        for (int n = 0; n < 8; ++n)
          acc[m][n] = __builtin_amdgcn_mfma_f32_16x16x32_bf16(af[m], bw[n], acc[m][n], 0, 0, 0);
    }
  }

  const int lr = (lane >> 4) * 4, lc = lane & 15;
#pragma unroll
  for (int m = 0; m < 4; ++m) {
#pragma unroll
    for (int j = 0; j < 4; ++j) {
      int r = tm * 128 + wr * 64 + m * 16 + lr + j;
      if (r < nrows) {
        size_t rowoff = (size_t)(seg0 + r) * H_DIM;
#pragma unroll
        for (int n = 0; n < 8; ++n)
          ybuf[rowoff + tn * 256 + wc * 128 + n * 16 + lc] = f2bf(acc[m][n][j]);
      }
    }
  }
}

// ---------------------------------------------------------------- combine
__global__ __launch_bounds__(256) void combine_kernel(
    const unsigned short* __restrict__ ybuf, const int* __restrict__ rowmap,
    const float* __restrict__ tw, float* __restrict__ out) {
  int t = blockIdx.x, tid = threadIdx.x;
  __shared__ int rloc[4];
  __shared__ float wloc[4];
  if (tid < 4) { rloc[tid] = rowmap[t * 4 + tid]; wloc[tid] = tw[t * 4 + tid]; }
  __syncthreads();
  int c = tid * 4;   // 256 threads x 4 cols = 1024
  float4 a = {0.f, 0.f, 0.f, 0.f};
#pragma unroll
  for (int k = 0; k < 4; ++k) {
    ushort4 v = *(const ushort4*)&ybuf[(size_t)rloc[k] * H_DIM + c];
    float w = wloc[k];
    a.x += w * bf2f(v.x); a.y += w * bf2f(v.y);
    a.z += w * bf2f(v.z); a.w += w * bf2f(v.w);
  }
  *(float4*)&out[(size_t)t * H_DIM + c] = a;
}

// ---------------------------------------------------------------- launch
extern "C" void kernel_launch(void* const* d_in, const int* in_sizes, int n_in,
                              void* d_out, int out_size, void* d_ws, size_t ws_size,
                              hipStream_t stream) {
  (void)in_sizes; (void)n_in; (void)out_size; (void)ws_size;
  const float* x  = (const float*)d_in[0];
  const float* rw = (const float*)d_in[1];
  const float* rb = (const float*)d_in[2];
  const float* wg = (const float*)d_in[3];
  const float* wu = (const float*)d_in[4];
  const float* wd = (const float*)d_in[5];
  float* out = (float*)d_out;

  char* base = (char*)d_ws;
  size_t o = 0;
  auto alloc = [&](size_t b) -> void* {
    void* p = base + o;
    o += (b + 255) & ~(size_t)255;
    return p;
  };
  unsigned short* xbf   = (unsigned short*)alloc((size_t)T_TOK * H_DIM * 2);
  unsigned short* wgbf  = (unsigned short*)alloc((size_t)E_EXP * I_DIM * H_DIM * 2);
  unsigned short* wubf  = (unsigned short*)alloc((size_t)E_EXP * I_DIM * H_DIM * 2);
  unsigned short* wdbf  = (unsigned short*)alloc((size_t)E_EXP * H_DIM * I_DIM * 2);
  unsigned short* hbuf  = (unsigned short*)alloc((size_t)T_TOK * TOPK * I_DIM * 2);
  unsigned short* ybuf  = (unsigned short*)alloc((size_t)T_TOK * TOPK * H_DIM * 2);
  float* logits = (float*)alloc((size_t)T_TOK * E_EXP * 4);
  int*   tidx   = (int*)alloc((size_t)T_TOK * TOPK * 4);
  float* tw     = (float*)alloc((size_t)T_TOK * TOPK * 4);
  int*   rowmap = (int*)alloc((size_t)T_TOK * TOPK * 4);
  int*   rowtok = (int*)alloc((size_t)T_TOK * TOPK * 4);
  int*   counts = (int*)alloc(256);
  int*   offb   = (int*)alloc(256);
  int*   toffb  = (int*)alloc(256);

  cvt_all_kernel<<<2048, 256, 0, stream>>>(x, xbf, wg, wgbf, wu, wubf, wd, wdbf);

  logits_kernel<<<T_TOK / 4, 256, 0, stream>>>(x, rw, logits);
  select_kernel<<<T_TOK / 256, 256, 0, stream>>>(logits, rb, tidx, tw);
  count_kernel<<<E_EXP, 256, 0, stream>>>(tidx, counts);
  prefix_kernel<<<1, 64, 0, stream>>>(counts, offb, toffb);
  scatter_kernel<<<E_EXP, 256, 0, stream>>>(tidx, offb, rowmap, rowtok);

  gateup_kernel<<<GEMM_GRID, 256, 0, stream>>>(xbf, wgbf, wubf, rowtok, offb, toffb, hbuf);
  down_kernel<<<GEMM_GRID, 256, 0, stream>>>(hbuf, wdbf, offb, toffb, ybuf);
  combine_kernel<<<T_TOK, 256, 0, stream>>>(ybuf, rowmap, tw, out);
}

// Round 8
// 157.732 us; speedup vs baseline: 1.1144x; 1.1144x over previous
//
#include <hip/hip_runtime.h>
#include <stdint.h>

// Problem constants (B=2, S=2048 -> T=4096 tokens)
#define T_TOK   4096
#define H_DIM   1024
#define I_DIM   512
#define E_EXP   16
#define TOPK    4
#define NTILEMAX 144   // >= max total 128-row M-tiles (<=143); 8*144=1152 blocks

typedef __attribute__((ext_vector_type(8))) short bf16x8;   // 8 bf16 = 4 VGPR
typedef __attribute__((ext_vector_type(4))) float f32x4;    // MFMA 16x16 acc
typedef __attribute__((ext_vector_type(8))) unsigned short ushort8;

__device__ __forceinline__ unsigned short f2bf(float f) {
  unsigned u = __float_as_uint(f);
  u = u + 0x7fffu + ((u >> 16) & 1u);          // RNE
  return (unsigned short)(u >> 16);
}
__device__ __forceinline__ float bf2f(unsigned short s) {
  return __uint_as_float(((unsigned)s) << 16);
}

__device__ __forceinline__ void gload_lds16(const void* g, void* l) {
  __builtin_amdgcn_global_load_lds(
      (const __attribute__((address_space(1))) unsigned int*)g,
      (__attribute__((address_space(3))) unsigned int*)l, 16, 0, 0);
}

// ---------------------------------------------------------------- convert
// Weights only (x is converted inside logits_kernel). 32B/lane/iter.
__device__ __forceinline__ void cvt_seg8(const float* __restrict__ src,
                                         unsigned short* __restrict__ dst,
                                         int n8, int tid0, int stride) {
  for (int i = tid0; i < n8; i += stride) {
    float4 v0 = ((const float4*)src)[2 * i];
    float4 v1 = ((const float4*)src)[2 * i + 1];
    ushort8 o;
    o[0] = f2bf(v0.x); o[1] = f2bf(v0.y); o[2] = f2bf(v0.z); o[3] = f2bf(v0.w);
    o[4] = f2bf(v1.x); o[5] = f2bf(v1.y); o[6] = f2bf(v1.z); o[7] = f2bf(v1.w);
    ((ushort8*)dst)[i] = o;
  }
}

__global__ __launch_bounds__(256) void cvt_w_kernel(
    const float* __restrict__ wg, unsigned short* __restrict__ wgb,
    const float* __restrict__ wu, unsigned short* __restrict__ wub,
    const float* __restrict__ wd, unsigned short* __restrict__ wdb) {
  const int tid0 = blockIdx.x * blockDim.x + threadIdx.x;
  const int stride = gridDim.x * blockDim.x;
  cvt_seg8(wg, wgb, E_EXP * I_DIM * H_DIM / 8, tid0, stride);
  cvt_seg8(wu, wub, E_EXP * I_DIM * H_DIM / 8, tid0, stride);
  cvt_seg8(wd, wdb, E_EXP * H_DIM * I_DIM / 8, tid0, stride);
}

// ---------------------------------------------------------------- router 1/4
// Wave per token: router logits AND bf16 conversion of the x row (fused —
// the row is already in registers).
__global__ __launch_bounds__(256) void logits_kernel(
    const float* __restrict__ x, const float* __restrict__ rw,
    float* __restrict__ logits, unsigned short* __restrict__ xb) {
  const int t = blockIdx.x * 4 + (threadIdx.x >> 6);
  const int lane = threadIdx.x & 63;
  const float* xr = x + (size_t)t * H_DIM;

  float4 xv[4];
#pragma unroll
  for (int i = 0; i < 4; ++i) xv[i] = ((const float4*)xr)[i * 64 + lane];

  // fused x -> bf16 (same coalescing as the load)
  unsigned short* xrow = xb + (size_t)t * H_DIM;
#pragma unroll
  for (int i = 0; i < 4; ++i) {
    ushort4 o;
    o.x = f2bf(xv[i].x); o.y = f2bf(xv[i].y);
    o.z = f2bf(xv[i].z); o.w = f2bf(xv[i].w);
    ((ushort4*)xrow)[i * 64 + lane] = o;
  }

#pragma unroll
  for (int g = 0; g < 4; ++g) {
    float acc[4] = {0.f, 0.f, 0.f, 0.f};
#pragma unroll
    for (int e4 = 0; e4 < 4; ++e4) {
      const float* wrow = rw + (size_t)(g * 4 + e4) * H_DIM;
#pragma unroll
      for (int i = 0; i < 4; ++i) {
        float4 wv = ((const float4*)wrow)[i * 64 + lane];
        acc[e4] = fmaf(xv[i].x, wv.x, acc[e4]);
        acc[e4] = fmaf(xv[i].y, wv.y, acc[e4]);
        acc[e4] = fmaf(xv[i].z, wv.z, acc[e4]);
        acc[e4] = fmaf(xv[i].w, wv.w, acc[e4]);
      }
    }
#pragma unroll
    for (int e4 = 0; e4 < 4; ++e4)
#pragma unroll
      for (int off = 32; off > 0; off >>= 1) acc[e4] += __shfl_down(acc[e4], off, 64);
    if (lane == 0)
      ((float4*)(logits + (size_t)t * E_EXP))[g] =
          make_float4(acc[0], acc[1], acc[2], acc[3]);
  }
}

// ---------------------------------------------------------------- router 2/4
__global__ __launch_bounds__(256) void select_kernel(
    const float* __restrict__ logits, const float* __restrict__ rb,
    int* __restrict__ tidx, float* __restrict__ tw) {
  const int t = blockIdx.x * 256 + threadIdx.x;

  float sc[E_EXP], sch[E_EXP];
#pragma unroll
  for (int e = 0; e < E_EXP; ++e) {
    sc[e] = 1.f / (1.f + expf(-logits[(size_t)t * E_EXP + e]));
    sch[e] = sc[e] + rb[e];
  }

  float gsum[4];
#pragma unroll
  for (int g = 0; g < 4; ++g) {
    float m1 = -3e38f, m2 = -3e38f;
#pragma unroll
    for (int j = 0; j < 4; ++j) {
      float v = sch[g * 4 + j];
      if (v > m1) { m2 = m1; m1 = v; } else if (v > m2) { m2 = v; }
    }
    gsum[g] = m1 + m2;
  }
  int g1 = 0;
  for (int g = 1; g < 4; ++g) if (gsum[g] > gsum[g1]) g1 = g;
  int g2 = -1;
  for (int g = 0; g < 4; ++g)
    if (g != g1 && (g2 < 0 || gsum[g] > gsum[g2])) g2 = g;

  float cand[E_EXP];
#pragma unroll
  for (int e = 0; e < E_EXP; ++e)
    cand[e] = ((e >> 2) == g1 || (e >> 2) == g2) ? sch[e] : -1e9f;

  int idx[TOPK]; float wv[TOPK]; float wsum = 0.f;
#pragma unroll
  for (int k = 0; k < TOPK; ++k) {
    int bi = 0; float bv = cand[0];
#pragma unroll
    for (int e = 1; e < E_EXP; ++e) if (cand[e] > bv) { bv = cand[e]; bi = e; }
    idx[k] = bi; cand[bi] = -3e38f;
    wv[k] = sc[bi];
    wsum += wv[k];
  }
  float scale = 2.5f / (wsum + 1e-20f);
#pragma unroll
  for (int k = 0; k < TOPK; ++k) {
    tidx[t * 4 + k] = idx[k];
    tw[t * 4 + k] = wv[k] * scale;
  }
}

// ---------------------------------------------------------------- router 3/4
__global__ __launch_bounds__(256) void count_kernel(
    const int* __restrict__ tidx, int* __restrict__ counts) {
  const int e = blockIdx.x, tid = threadIdx.x;
  const int lane = tid & 63, wv = tid >> 6;
  int local = 0;
  for (int i = tid; i < T_TOK * TOPK; i += 256) local += (tidx[i] == e);
#pragma unroll
  for (int off = 32; off > 0; off >>= 1) local += __shfl_down(local, off, 64);
  __shared__ int ws[4];
  if (lane == 0) ws[wv] = local;
  __syncthreads();
  if (tid == 0) counts[e] = ws[0] + ws[1] + ws[2] + ws[3];
}

// prefix over rows AND over 128-row M-tiles (compact dispatch table)
__global__ void prefix_kernel(const int* __restrict__ counts,
                              int* __restrict__ off, int* __restrict__ toff) {
  if (threadIdx.x == 0) {
    int a = 0, tt = 0;
    for (int e = 0; e < E_EXP; ++e) {
      off[e] = a; toff[e] = tt;
      a += counts[e];
      tt += (counts[e] + 127) >> 7;
    }
    off[E_EXP] = a;                 // == 4*T
    toff[E_EXP] = tt;               // total M-tiles (<= 143)
  }
}

// ---------------------------------------------------------------- router 4/4
__global__ __launch_bounds__(256) void scatter_kernel(
    const int* __restrict__ tidx, const int* __restrict__ off,
    int* __restrict__ rowmap, int* __restrict__ rowtok) {
  const int e = blockIdx.x, tid = threadIdx.x;
  const int lane = tid & 63, wv = tid >> 6;
  __shared__ int wsum[4];
  __shared__ int srun;
  if (tid == 0) srun = 0;
  __syncthreads();
  const int base = off[e];
  for (int c = 0; c < T_TOK * TOPK / 256; ++c) {
    const int i = c * 256 + tid;
    const bool f = (tidx[i] == e);
    unsigned long long m = __ballot(f);
    int wpre = __popcll(m & ((1ull << lane) - 1ull));
    if (lane == 63) wsum[wv] = wpre + (f ? 1 : 0);
    __syncthreads();
    const int run = srun;
    int pre = 0, tot = 0;
#pragma unroll
    for (int w = 0; w < 4; ++w) {
      int v = wsum[w];
      if (w < wv) pre += v;
      tot += v;
    }
    if (f) {
      const int pos = base + run + pre + wpre;
      rowmap[i] = pos;
      rowtok[pos] = i >> 2;
    }
    __syncthreads();
    if (tid == 0) srun = run + tot;
  }
}

// decode compact tile id -> expert (monotone table walk, branchless)
__device__ __forceinline__ int find_expert(const int* __restrict__ toff, int tile) {
  int e = 0;
#pragma unroll
  for (int q = 1; q <= E_EXP; ++q) e += (toff[q] <= tile);
  return e;
}

// ---------------------------------------------------------------- gate+up GEMM
// Round-6 proven config: tile 128(M)x64(N of I), BK=64, dual acc, 4 waves 2x2,
// single-buffer 2-barrier loop, T2 swizzle, compact dispatch, XCD chunk, 3/CU.
__global__ __launch_bounds__(256, 3) void gateup_kernel(
    const unsigned short* __restrict__ xbf,   // [T,H]
    const unsigned short* __restrict__ wgbf,  // [E,I,H]
    const unsigned short* __restrict__ wubf,  // [E,I,H]
    const int* __restrict__ rowtok, const int* __restrict__ off,
    const int* __restrict__ toff,
    unsigned short* __restrict__ hbuf) {      // [4T,I]
  const int bid = (int)blockIdx.x;
  const int work = (bid & 7) * NTILEMAX + (bid >> 3);
  const int tile = work >> 3, tn = work & 7;
  if (tile >= toff[E_EXP]) return;
  const int e = find_expert(toff, tile);
  const int tm = tile - toff[e];
  const int seg0 = off[e];
  const int nrows = off[e + 1] - seg0;

  __shared__ __align__(16) unsigned short As[128 * 64];  // 16KB
  __shared__ __align__(16) unsigned short Gs[64 * 64];   // 8KB
  __shared__ __align__(16) unsigned short Us[64 * 64];   // 8KB
  __shared__ int ids[128];

  const int tid = threadIdx.x;
  if (tid < 128) {
    int r = tm * 128 + tid;
    ids[tid] = rowtok[seg0 + (r < nrows ? r : 0)];       // clamp: safe read
  }
  __syncthreads();

  const int col8 = tid & 7;        // 16B chunk within a 64-elem row
  const int r0 = tid >> 3;         // row base within 32-row stripe
  const int csrc = (col8 ^ (r0 & 7)) * 8;  // pre-swizzled source column
  int tokA[4];
#pragma unroll
  for (int j = 0; j < 4; ++j) tokA[j] = ids[j * 32 + r0];

  const unsigned short* wg = wgbf + (size_t)e * I_DIM * H_DIM + (size_t)(tn * 64) * H_DIM;
  const unsigned short* wu = wubf + (size_t)e * I_DIM * H_DIM + (size_t)(tn * 64) * H_DIM;

  f32x4 accg[4][2], accu[4][2];
#pragma unroll
  for (int m = 0; m < 4; ++m)
#pragma unroll
    for (int n = 0; n < 2; ++n) { accg[m][n] = (f32x4)0.f; accu[m][n] = (f32x4)0.f; }

  const int lane = tid & 63, wid = tid >> 6;
  const int wr = wid >> 1, wc = wid & 1;
  const int frow = lane & 15, fr7 = frow & 7;
  const int kc = lane >> 4;        // base chunk (0..3) within K=64 row

  for (int kt = 0; kt < H_DIM / 64; ++kt) {
    const int kb = kt * 64 + csrc;
    __syncthreads();                         // prev compute done
#pragma unroll
    for (int j = 0; j < 4; ++j)
      gload_lds16(xbf + ((size_t)tokA[j] * H_DIM + kb), (char*)As + (j * 256 + tid) * 16);
#pragma unroll
    for (int j = 0; j < 2; ++j) {
      gload_lds16(wg + ((size_t)(j * 32 + r0) * H_DIM + kb), (char*)Gs + (j * 256 + tid) * 16);
      gload_lds16(wu + ((size_t)(j * 32 + r0) * H_DIM + kb), (char*)Us + (j * 256 + tid) * 16);
    }
    __syncthreads();                         // vmcnt(0) drained by compiler
#pragma unroll
    for (int kk = 0; kk < 2; ++kk) {
      const int swz = ((kk * 4 + kc) ^ fr7) * 8;   // swizzled elem offset
      bf16x8 af[4], bg[2], bu[2];
#pragma unroll
      for (int m = 0; m < 4; ++m)
        af[m] = *(const bf16x8*)&As[(wr * 64 + m * 16 + frow) * 64 + swz];
#pragma unroll
      for (int n = 0; n < 2; ++n) {
        bg[n] = *(const bf16x8*)&Gs[(wc * 32 + n * 16 + frow) * 64 + swz];
        bu[n] = *(const bf16x8*)&Us[(wc * 32 + n * 16 + frow) * 64 + swz];
      }
#pragma unroll
      for (int m = 0; m < 4; ++m)
#pragma unroll
        for (int n = 0; n < 2; ++n) {
          accg[m][n] = __builtin_amdgcn_mfma_f32_16x16x32_bf16(af[m], bg[n], accg[m][n], 0, 0, 0);
          accu[m][n] = __builtin_amdgcn_mfma_f32_16x16x32_bf16(af[m], bu[n], accu[m][n], 0, 0, 0);
        }
    }
  }

  // epilogue: h = silu(g)*u  (C/D layout: col=lane&15, row=(lane>>4)*4+j)
  const int lr = (lane >> 4) * 4, lc = lane & 15;
#pragma unroll
  for (int m = 0; m < 4; ++m) {
#pragma unroll
    for (int j = 0; j < 4; ++j) {
      int r = tm * 128 + wr * 64 + m * 16 + lr + j;
      if (r < nrows) {
        size_t rowoff = (size_t)(seg0 + r) * I_DIM;
#pragma unroll
        for (int n = 0; n < 2; ++n) {
          float g = accg[m][n][j];
          float u = accu[m][n][j];
          float hv = g / (1.f + __expf(-g)) * u;
          hbuf[rowoff + tn * 64 + wc * 32 + n * 16 + lc] = f2bf(hv);
        }
      }
    }
  }
}

// ---------------------------------------------------------------- down GEMM
// Round-6 proven config: tile 128x128, BK=64 over I, 3/CU.
__global__ __launch_bounds__(256, 3) void down_kernel(
    const unsigned short* __restrict__ hbuf,  // [4T,I]
    const unsigned short* __restrict__ wdbf,  // [E,H,I]
    const int* __restrict__ off, const int* __restrict__ toff,
    unsigned short* __restrict__ ybuf) {      // [4T,H]
  const int bid = (int)blockIdx.x;
  const int work = (bid & 7) * NTILEMAX + (bid >> 3);
  const int tile = work >> 3, tn = work & 7;
  if (tile >= toff[E_EXP]) return;
  const int e = find_expert(toff, tile);
  const int tm = tile - toff[e];
  const int seg0 = off[e];
  const int nrows = off[e + 1] - seg0;

  __shared__ __align__(16) unsigned short As[128 * 64];  // 16KB
  __shared__ __align__(16) unsigned short Bs[128 * 64];  // 16KB

  const int tid = threadIdx.x;
  const int col8 = tid & 7;
  const int r0 = tid >> 3;
  const int csrc = (col8 ^ (r0 & 7)) * 8;
  int rowA[4];
#pragma unroll
  for (int j = 0; j < 4; ++j) {
    int r = tm * 128 + j * 32 + r0;
    rowA[j] = seg0 + (r < nrows ? r : nrows - 1);
  }
  const unsigned short* wd = wdbf + (size_t)e * H_DIM * I_DIM + (size_t)(tn * 128) * I_DIM;

  f32x4 acc[4][4];
#pragma unroll
  for (int m = 0; m < 4; ++m)
#pragma unroll
    for (int n = 0; n < 4; ++n) acc[m][n] = (f32x4)0.f;

  const int lane = tid & 63, wid = tid >> 6;
  const int wr = wid >> 1, wc = wid & 1;
  const int frow = lane & 15, fr7 = frow & 7;
  const int kc = lane >> 4;

  for (int kt = 0; kt < I_DIM / 64; ++kt) {
    const int kb = kt * 64 + csrc;
    __syncthreads();
#pragma unroll
    for (int j = 0; j < 4; ++j) {
      gload_lds16(hbuf + ((size_t)rowA[j] * I_DIM + kb), (char*)As + (j * 256 + tid) * 16);
      gload_lds16(wd + ((size_t)(j * 32 + r0) * I_DIM + kb), (char*)Bs + (j * 256 + tid) * 16);
    }
    __syncthreads();
#pragma unroll
    for (int kk = 0; kk < 2; ++kk) {
      const int swz = ((kk * 4 + kc) ^ fr7) * 8;
      bf16x8 af[4], bw[4];
#pragma unroll
      for (int m = 0; m < 4; ++m)
        af[m] = *(const bf16x8*)&As[(wr * 64 + m * 16 + frow) * 64 + swz];
#pragma unroll
      for (int n = 0; n < 4; ++n)
        bw[n] = *(const bf16x8*)&Bs[(wc * 64 + n * 16 + frow) * 64 + swz];
#pragma unroll
      for (int m = 0; m < 4; ++m)
#pragma unroll
        for (int n = 0; n < 4; ++n)
          acc[m][n] = __builtin_amdgcn_mfma_f32_16x16x32_bf16(af[m], bw[n], acc[m][n], 0, 0, 0);
    }
  }

  const int lr = (lane >> 4) * 4, lc = lane & 15;
#pragma unroll
  for (int m = 0; m < 4; ++m) {
#pragma unroll
    for (int j = 0; j < 4; ++j) {
      int r = tm * 128 + wr * 64 + m * 16 + lr + j;
      if (r < nrows) {
        size_t rowoff = (size_t)(seg0 + r) * H_DIM;
#pragma unroll
        for (int n = 0; n < 4; ++n)
          ybuf[rowoff + tn * 128 + wc * 64 + n * 16 + lc] = f2bf(acc[m][n][j]);
      }
    }
  }
}

// ---------------------------------------------------------------- combine
__global__ __launch_bounds__(256) void combine_kernel(
    const unsigned short* __restrict__ ybuf, const int* __restrict__ rowmap,
    const float* __restrict__ tw, float* __restrict__ out) {
  int t = blockIdx.x, tid = threadIdx.x;
  __shared__ int rloc[4];
  __shared__ float wloc[4];
  if (tid < 4) { rloc[tid] = rowmap[t * 4 + tid]; wloc[tid] = tw[t * 4 + tid]; }
  __syncthreads();
  int c = tid * 4;   // 256 threads x 4 cols = 1024
  float4 a = {0.f, 0.f, 0.f, 0.f};
#pragma unroll
  for (int k = 0; k < 4; ++k) {
    ushort4 v = *(const ushort4*)&ybuf[(size_t)rloc[k] * H_DIM + c];
    float w = wloc[k];
    a.x += w * bf2f(v.x); a.y += w * bf2f(v.y);
    a.z += w * bf2f(v.z); a.w += w * bf2f(v.w);
  }
  *(float4*)&out[(size_t)t * H_DIM + c] = a;
}

// ---------------------------------------------------------------- launch
extern "C" void kernel_launch(void* const* d_in, const int* in_sizes, int n_in,
                              void* d_out, int out_size, void* d_ws, size_t ws_size,
                              hipStream_t stream) {
  (void)in_sizes; (void)n_in; (void)out_size; (void)ws_size;
  const float* x  = (const float*)d_in[0];
  const float* rw = (const float*)d_in[1];
  const float* rb = (const float*)d_in[2];
  const float* wg = (const float*)d_in[3];
  const float* wu = (const float*)d_in[4];
  const float* wd = (const float*)d_in[5];
  float* out = (float*)d_out;

  char* base = (char*)d_ws;
  size_t o = 0;
  auto alloc = [&](size_t b) -> void* {
    void* p = base + o;
    o += (b + 255) & ~(size_t)255;
    return p;
  };
  unsigned short* xbf   = (unsigned short*)alloc((size_t)T_TOK * H_DIM * 2);
  unsigned short* wgbf  = (unsigned short*)alloc((size_t)E_EXP * I_DIM * H_DIM * 2);
  unsigned short* wubf  = (unsigned short*)alloc((size_t)E_EXP * I_DIM * H_DIM * 2);
  unsigned short* wdbf  = (unsigned short*)alloc((size_t)E_EXP * H_DIM * I_DIM * 2);
  unsigned short* hbuf  = (unsigned short*)alloc((size_t)T_TOK * TOPK * I_DIM * 2);
  unsigned short* ybuf  = (unsigned short*)alloc((size_t)T_TOK * TOPK * H_DIM * 2);
  float* logits = (float*)alloc((size_t)T_TOK * E_EXP * 4);
  int*   tidx   = (int*)alloc((size_t)T_TOK * TOPK * 4);
  float* tw     = (float*)alloc((size_t)T_TOK * TOPK * 4);
  int*   rowmap = (int*)alloc((size_t)T_TOK * TOPK * 4);
  int*   rowtok = (int*)alloc((size_t)T_TOK * TOPK * 4);
  int*   counts = (int*)alloc(256);
  int*   offb   = (int*)alloc(256);
  int*   toffb  = (int*)alloc(256);

  cvt_w_kernel<<<2048, 256, 0, stream>>>(wg, wgbf, wu, wubf, wd, wdbf);

  logits_kernel<<<T_TOK / 4, 256, 0, stream>>>(x, rw, logits, xbf);
  select_kernel<<<T_TOK / 256, 256, 0, stream>>>(logits, rb, tidx, tw);
  count_kernel<<<E_EXP, 256, 0, stream>>>(tidx, counts);
  prefix_kernel<<<1, 64, 0, stream>>>(counts, offb, toffb);
  scatter_kernel<<<E_EXP, 256, 0, stream>>>(tidx, offb, rowmap, rowtok);

  gateup_kernel<<<8 * NTILEMAX, 256, 0, stream>>>(xbf, wgbf, wubf, rowtok, offb, toffb, hbuf);
  down_kernel<<<8 * NTILEMAX, 256, 0, stream>>>(hbuf, wdbf, offb, toffb, ybuf);
  combine_kernel<<<T_TOK, 256, 0, stream>>>(ybuf, rowmap, tw, out);
}

// Round 9
// 156.388 us; speedup vs baseline: 1.1240x; 1.0086x over previous
//
#include <hip/hip_runtime.h>
#include <stdint.h>

// Problem constants (B=2, S=2048 -> T=4096 tokens)
#define T_TOK   4096
#define H_DIM   1024
#define I_DIM   512
#define E_EXP   16
#define TOPK    4
#define NTILEMAX 144   // >= max total 128-row M-tiles (<=143); 8*144=1152 blocks

typedef __attribute__((ext_vector_type(8))) short bf16x8;   // 8 bf16 = 4 VGPR
typedef __attribute__((ext_vector_type(4))) float f32x4;    // MFMA 16x16 acc
typedef __attribute__((ext_vector_type(8))) unsigned short ushort8;

__device__ __forceinline__ unsigned short f2bf(float f) {
  unsigned u = __float_as_uint(f);
  u = u + 0x7fffu + ((u >> 16) & 1u);          // RNE
  return (unsigned short)(u >> 16);
}
__device__ __forceinline__ float bf2f(unsigned short s) {
  return __uint_as_float(((unsigned)s) << 16);
}

// pack 2 fp32 -> 2 bf16 in one dword (RNE), gfx950 HW instruction
__device__ __forceinline__ unsigned cvtpk(float lo, float hi) {
  unsigned r;
  asm("v_cvt_pk_bf16_f32 %0, %1, %2" : "=v"(r) : "v"(lo), "v"(hi));
  return r;
}

__device__ __forceinline__ void gload_lds16(const void* g, void* l) {
  __builtin_amdgcn_global_load_lds(
      (const __attribute__((address_space(1))) unsigned int*)g,
      (__attribute__((address_space(3))) unsigned int*)l, 16, 0, 0);
}

// ---------------------------------------------------------------- router 1/4
// Wave per token: router logits AND bf16 conversion of the x row (fused —
// the row is already in registers).
__global__ __launch_bounds__(256) void logits_kernel(
    const float* __restrict__ x, const float* __restrict__ rw,
    float* __restrict__ logits, unsigned short* __restrict__ xb) {
  const int t = blockIdx.x * 4 + (threadIdx.x >> 6);
  const int lane = threadIdx.x & 63;
  const float* xr = x + (size_t)t * H_DIM;

  float4 xv[4];
#pragma unroll
  for (int i = 0; i < 4; ++i) xv[i] = ((const float4*)xr)[i * 64 + lane];

  // fused x -> bf16 (same coalescing as the load)
  unsigned short* xrow = xb + (size_t)t * H_DIM;
#pragma unroll
  for (int i = 0; i < 4; ++i) {
    ushort4 o;
    o.x = f2bf(xv[i].x); o.y = f2bf(xv[i].y);
    o.z = f2bf(xv[i].z); o.w = f2bf(xv[i].w);
    ((ushort4*)xrow)[i * 64 + lane] = o;
  }

#pragma unroll
  for (int g = 0; g < 4; ++g) {
    float acc[4] = {0.f, 0.f, 0.f, 0.f};
#pragma unroll
    for (int e4 = 0; e4 < 4; ++e4) {
      const float* wrow = rw + (size_t)(g * 4 + e4) * H_DIM;
#pragma unroll
      for (int i = 0; i < 4; ++i) {
        float4 wv = ((const float4*)wrow)[i * 64 + lane];
        acc[e4] = fmaf(xv[i].x, wv.x, acc[e4]);
        acc[e4] = fmaf(xv[i].y, wv.y, acc[e4]);
        acc[e4] = fmaf(xv[i].z, wv.z, acc[e4]);
        acc[e4] = fmaf(xv[i].w, wv.w, acc[e4]);
      }
    }
#pragma unroll
    for (int e4 = 0; e4 < 4; ++e4)
#pragma unroll
      for (int off = 32; off > 0; off >>= 1) acc[e4] += __shfl_down(acc[e4], off, 64);
    if (lane == 0)
      ((float4*)(logits + (size_t)t * E_EXP))[g] =
          make_float4(acc[0], acc[1], acc[2], acc[3]);
  }
}

// ---------------------------------------------------------------- router 2/4
__global__ __launch_bounds__(256) void select_kernel(
    const float* __restrict__ logits, const float* __restrict__ rb,
    int* __restrict__ tidx, float* __restrict__ tw) {
  const int t = blockIdx.x * 256 + threadIdx.x;

  float sc[E_EXP], sch[E_EXP];
#pragma unroll
  for (int e = 0; e < E_EXP; ++e) {
    sc[e] = 1.f / (1.f + expf(-logits[(size_t)t * E_EXP + e]));
    sch[e] = sc[e] + rb[e];
  }

  float gsum[4];
#pragma unroll
  for (int g = 0; g < 4; ++g) {
    float m1 = -3e38f, m2 = -3e38f;
#pragma unroll
    for (int j = 0; j < 4; ++j) {
      float v = sch[g * 4 + j];
      if (v > m1) { m2 = m1; m1 = v; } else if (v > m2) { m2 = v; }
    }
    gsum[g] = m1 + m2;
  }
  int g1 = 0;
  for (int g = 1; g < 4; ++g) if (gsum[g] > gsum[g1]) g1 = g;
  int g2 = -1;
  for (int g = 0; g < 4; ++g)
    if (g != g1 && (g2 < 0 || gsum[g] > gsum[g2])) g2 = g;

  float cand[E_EXP];
#pragma unroll
  for (int e = 0; e < E_EXP; ++e)
    cand[e] = ((e >> 2) == g1 || (e >> 2) == g2) ? sch[e] : -1e9f;

  int idx[TOPK]; float wv[TOPK]; float wsum = 0.f;
#pragma unroll
  for (int k = 0; k < TOPK; ++k) {
    int bi = 0; float bv = cand[0];
#pragma unroll
    for (int e = 1; e < E_EXP; ++e) if (cand[e] > bv) { bv = cand[e]; bi = e; }
    idx[k] = bi; cand[bi] = -3e38f;
    wv[k] = sc[bi];
    wsum += wv[k];
  }
  float scale = 2.5f / (wsum + 1e-20f);
#pragma unroll
  for (int k = 0; k < TOPK; ++k) {
    tidx[t * 4 + k] = idx[k];
    tw[t * 4 + k] = wv[k] * scale;
  }
}

// ---------------------------------------------------------------- router 3/4
__global__ __launch_bounds__(256) void count_kernel(
    const int* __restrict__ tidx, int* __restrict__ counts) {
  const int e = blockIdx.x, tid = threadIdx.x;
  const int lane = tid & 63, wv = tid >> 6;
  int local = 0;
  for (int i = tid; i < T_TOK * TOPK; i += 256) local += (tidx[i] == e);
#pragma unroll
  for (int off = 32; off > 0; off >>= 1) local += __shfl_down(local, off, 64);
  __shared__ int ws[4];
  if (lane == 0) ws[wv] = local;
  __syncthreads();
  if (tid == 0) counts[e] = ws[0] + ws[1] + ws[2] + ws[3];
}

// prefix over rows AND over 128-row M-tiles (compact dispatch table)
__global__ void prefix_kernel(const int* __restrict__ counts,
                              int* __restrict__ off, int* __restrict__ toff) {
  if (threadIdx.x == 0) {
    int a = 0, tt = 0;
    for (int e = 0; e < E_EXP; ++e) {
      off[e] = a; toff[e] = tt;
      a += counts[e];
      tt += (counts[e] + 127) >> 7;
    }
    off[E_EXP] = a;                 // == 4*T
    toff[E_EXP] = tt;               // total M-tiles (<= 143)
  }
}

// ---------------------------------------------------------------- router 4/4
__global__ __launch_bounds__(256) void scatter_kernel(
    const int* __restrict__ tidx, const int* __restrict__ off,
    int* __restrict__ rowmap, int* __restrict__ rowtok) {
  const int e = blockIdx.x, tid = threadIdx.x;
  const int lane = tid & 63, wv = tid >> 6;
  __shared__ int wsum[4];
  __shared__ int srun;
  if (tid == 0) srun = 0;
  __syncthreads();
  const int base = off[e];
  for (int c = 0; c < T_TOK * TOPK / 256; ++c) {
    const int i = c * 256 + tid;
    const bool f = (tidx[i] == e);
    unsigned long long m = __ballot(f);
    int wpre = __popcll(m & ((1ull << lane) - 1ull));
    if (lane == 63) wsum[wv] = wpre + (f ? 1 : 0);
    __syncthreads();
    const int run = srun;
    int pre = 0, tot = 0;
#pragma unroll
    for (int w = 0; w < 4; ++w) {
      int v = wsum[w];
      if (w < wv) pre += v;
      tot += v;
    }
    if (f) {
      const int pos = base + run + pre + wpre;
      rowmap[i] = pos;
      rowtok[pos] = i >> 2;
    }
    __syncthreads();
    if (tid == 0) srun = run + tot;
  }
}

// decode compact tile id -> expert (monotone table walk, branchless)
__device__ __forceinline__ int find_expert(const int* __restrict__ toff, int tile) {
  int e = 0;
#pragma unroll
  for (int q = 1; q <= E_EXP; ++q) e += (toff[q] <= tile);
  return e;
}

// ---------------------------------------------------------------- gate+up GEMM
// Round-6 structure (tile 128x64, BK=64, 2-barrier, 3/CU) with IN-KERNEL
// fp32->bf16 weight conversion: A via gload_lds (pre-swizzled source), B via
// reg-staging (linear fp32 float4 loads -> cvt_pk -> swizzled ds_write_b128).
__global__ __launch_bounds__(256, 3) void gateup_kernel(
    const unsigned short* __restrict__ xbf,   // [T,H] bf16
    const float* __restrict__ wgf,            // [E,I,H] fp32
    const float* __restrict__ wuf,            // [E,I,H] fp32
    const int* __restrict__ rowtok, const int* __restrict__ off,
    const int* __restrict__ toff,
    unsigned short* __restrict__ hbuf) {      // [4T,I]
  const int bid = (int)blockIdx.x;
  const int work = (bid & 7) * NTILEMAX + (bid >> 3);
  const int tile = work >> 3, tn = work & 7;
  if (tile >= toff[E_EXP]) return;
  const int e = find_expert(toff, tile);
  const int tm = tile - toff[e];
  const int seg0 = off[e];
  const int nrows = off[e + 1] - seg0;

  __shared__ __align__(16) unsigned short As[128 * 64];  // 16KB
  __shared__ __align__(16) unsigned short Gs[64 * 64];   // 8KB
  __shared__ __align__(16) unsigned short Us[64 * 64];   // 8KB
  __shared__ int ids[128];

  const int tid = threadIdx.x;
  if (tid < 128) {
    int r = tm * 128 + tid;
    ids[tid] = rowtok[seg0 + (r < nrows ? r : 0)];       // clamp: safe read
  }
  __syncthreads();

  const int col8 = tid & 7;        // 16B chunk within a 64-elem row
  const int r0 = tid >> 3;         // row base within 32-row stripe
  const int csrc = (col8 ^ (r0 & 7)) * 8;  // pre-swizzled source column (A)
  const int bcol = col8 * 8;               // linear source column (B, fp32)
  const int bdst = (col8 ^ (r0 & 7)) * 8;  // swizzled LDS dest chunk (B)
  int tokA[4];
#pragma unroll
  for (int j = 0; j < 4; ++j) tokA[j] = ids[j * 32 + r0];

  const float* wg = wgf + (size_t)e * I_DIM * H_DIM + (size_t)(tn * 64) * H_DIM;
  const float* wu = wuf + (size_t)e * I_DIM * H_DIM + (size_t)(tn * 64) * H_DIM;

  f32x4 accg[4][2], accu[4][2];
#pragma unroll
  for (int m = 0; m < 4; ++m)
#pragma unroll
    for (int n = 0; n < 2; ++n) { accg[m][n] = (f32x4)0.f; accu[m][n] = (f32x4)0.f; }

  const int lane = tid & 63, wid = tid >> 6;
  const int wr = wid >> 1, wc = wid & 1;
  const int frow = lane & 15, fr7 = frow & 7;
  const int kc = lane >> 4;        // base chunk (0..3) within K=64 row

  for (int kt = 0; kt < H_DIM / 64; ++kt) {
    const int kbA = kt * 64 + csrc;
    const int kbB = kt * 64 + bcol;
    __syncthreads();                         // prev compute done
#pragma unroll
    for (int j = 0; j < 4; ++j)
      gload_lds16(xbf + ((size_t)tokA[j] * H_DIM + kbA), (char*)As + (j * 256 + tid) * 16);
#pragma unroll
    for (int j = 0; j < 2; ++j) {
      const int row = j * 32 + r0;
      const float4* gs = (const float4*)(wg + (size_t)row * H_DIM + kbB);
      const float4* us = (const float4*)(wu + (size_t)row * H_DIM + kbB);
      float4 g0 = gs[0], g1 = gs[1];
      float4 u0 = us[0], u1 = us[1];
      uint4 gw, uw;
      gw.x = cvtpk(g0.x, g0.y); gw.y = cvtpk(g0.z, g0.w);
      gw.z = cvtpk(g1.x, g1.y); gw.w = cvtpk(g1.z, g1.w);
      uw.x = cvtpk(u0.x, u0.y); uw.y = cvtpk(u0.z, u0.w);
      uw.z = cvtpk(u1.x, u1.y); uw.w = cvtpk(u1.z, u1.w);
      *(uint4*)&Gs[row * 64 + bdst] = gw;
      *(uint4*)&Us[row * 64 + bdst] = uw;
    }
    __syncthreads();                         // vmcnt+lgkmcnt drained by compiler
#pragma unroll
    for (int kk = 0; kk < 2; ++kk) {
      const int swz = ((kk * 4 + kc) ^ fr7) * 8;   // swizzled elem offset
      bf16x8 af[4], bg[2], bu[2];
#pragma unroll
      for (int m = 0; m < 4; ++m)
        af[m] = *(const bf16x8*)&As[(wr * 64 + m * 16 + frow) * 64 + swz];
#pragma unroll
      for (int n = 0; n < 2; ++n) {
        bg[n] = *(const bf16x8*)&Gs[(wc * 32 + n * 16 + frow) * 64 + swz];
        bu[n] = *(const bf16x8*)&Us[(wc * 32 + n * 16 + frow) * 64 + swz];
      }
#pragma unroll
      for (int m = 0; m < 4; ++m)
#pragma unroll
        for (int n = 0; n < 2; ++n) {
          accg[m][n] = __builtin_amdgcn_mfma_f32_16x16x32_bf16(af[m], bg[n], accg[m][n], 0, 0, 0);
          accu[m][n] = __builtin_amdgcn_mfma_f32_16x16x32_bf16(af[m], bu[n], accu[m][n], 0, 0, 0);
        }
    }
  }

  // epilogue: h = silu(g)*u  (C/D layout: col=lane&15, row=(lane>>4)*4+j)
  const int lr = (lane >> 4) * 4, lc = lane & 15;
#pragma unroll
  for (int m = 0; m < 4; ++m) {
#pragma unroll
    for (int j = 0; j < 4; ++j) {
      int r = tm * 128 + wr * 64 + m * 16 + lr + j;
      if (r < nrows) {
        size_t rowoff = (size_t)(seg0 + r) * I_DIM;
#pragma unroll
        for (int n = 0; n < 2; ++n) {
          float g = accg[m][n][j];
          float u = accu[m][n][j];
          float hv = g / (1.f + __expf(-g)) * u;
          hbuf[rowoff + tn * 64 + wc * 32 + n * 16 + lc] = f2bf(hv);
        }
      }
    }
  }
}

// ---------------------------------------------------------------- down GEMM
// Tile 128x128, BK=64 over I, 3/CU. A (hbuf) via gload_lds; B (wd) fp32
// reg-staged with in-kernel conversion.
__global__ __launch_bounds__(256, 3) void down_kernel(
    const unsigned short* __restrict__ hbuf,  // [4T,I] bf16
    const float* __restrict__ wdf,            // [E,H,I] fp32
    const int* __restrict__ off, const int* __restrict__ toff,
    unsigned short* __restrict__ ybuf) {      // [4T,H]
  const int bid = (int)blockIdx.x;
  const int work = (bid & 7) * NTILEMAX + (bid >> 3);
  const int tile = work >> 3, tn = work & 7;
  if (tile >= toff[E_EXP]) return;
  const int e = find_expert(toff, tile);
  const int tm = tile - toff[e];
  const int seg0 = off[e];
  const int nrows = off[e + 1] - seg0;

  __shared__ __align__(16) unsigned short As[128 * 64];  // 16KB
  __shared__ __align__(16) unsigned short Bs[128 * 64];  // 16KB

  const int tid = threadIdx.x;
  const int col8 = tid & 7;
  const int r0 = tid >> 3;
  const int csrc = (col8 ^ (r0 & 7)) * 8;
  const int bcol = col8 * 8;
  const int bdst = (col8 ^ (r0 & 7)) * 8;
  int rowA[4];
#pragma unroll
  for (int j = 0; j < 4; ++j) {
    int r = tm * 128 + j * 32 + r0;
    rowA[j] = seg0 + (r < nrows ? r : nrows - 1);
  }
  const float* wd = wdf + (size_t)e * H_DIM * I_DIM + (size_t)(tn * 128) * I_DIM;

  f32x4 acc[4][4];
#pragma unroll
  for (int m = 0; m < 4; ++m)
#pragma unroll
    for (int n = 0; n < 4; ++n) acc[m][n] = (f32x4)0.f;

  const int lane = tid & 63, wid = tid >> 6;
  const int wr = wid >> 1, wc = wid & 1;
  const int frow = lane & 15, fr7 = frow & 7;
  const int kc = lane >> 4;

  for (int kt = 0; kt < I_DIM / 64; ++kt) {
    const int kbA = kt * 64 + csrc;
    const int kbB = kt * 64 + bcol;
    __syncthreads();
#pragma unroll
    for (int j = 0; j < 4; ++j)
      gload_lds16(hbuf + ((size_t)rowA[j] * I_DIM + kbA), (char*)As + (j * 256 + tid) * 16);
#pragma unroll
    for (int j = 0; j < 4; ++j) {
      const int row = j * 32 + r0;
      const float4* ds = (const float4*)(wd + (size_t)row * I_DIM + kbB);
      float4 d0 = ds[0], d1 = ds[1];
      uint4 w;
      w.x = cvtpk(d0.x, d0.y); w.y = cvtpk(d0.z, d0.w);
      w.z = cvtpk(d1.x, d1.y); w.w = cvtpk(d1.z, d1.w);
      *(uint4*)&Bs[row * 64 + bdst] = w;
    }
    __syncthreads();
#pragma unroll
    for (int kk = 0; kk < 2; ++kk) {
      const int swz = ((kk * 4 + kc) ^ fr7) * 8;
      bf16x8 af[4], bw[4];
#pragma unroll
      for (int m = 0; m < 4; ++m)
        af[m] = *(const bf16x8*)&As[(wr * 64 + m * 16 + frow) * 64 + swz];
#pragma unroll
      for (int n = 0; n < 4; ++n)
        bw[n] = *(const bf16x8*)&Bs[(wc * 64 + n * 16 + frow) * 64 + swz];
#pragma unroll
      for (int m = 0; m < 4; ++m)
#pragma unroll
        for (int n = 0; n < 4; ++n)
          acc[m][n] = __builtin_amdgcn_mfma_f32_16x16x32_bf16(af[m], bw[n], acc[m][n], 0, 0, 0);
    }
  }

  const int lr = (lane >> 4) * 4, lc = lane & 15;
#pragma unroll
  for (int m = 0; m < 4; ++m) {
#pragma unroll
    for (int j = 0; j < 4; ++j) {
      int r = tm * 128 + wr * 64 + m * 16 + lr + j;
      if (r < nrows) {
        size_t rowoff = (size_t)(seg0 + r) * H_DIM;
#pragma unroll
        for (int n = 0; n < 4; ++n)
          ybuf[rowoff + tn * 128 + wc * 64 + n * 16 + lc] = f2bf(acc[m][n][j]);
      }
    }
  }
}

// ---------------------------------------------------------------- combine
__global__ __launch_bounds__(256) void combine_kernel(
    const unsigned short* __restrict__ ybuf, const int* __restrict__ rowmap,
    const float* __restrict__ tw, float* __restrict__ out) {
  int t = blockIdx.x, tid = threadIdx.x;
  __shared__ int rloc[4];
  __shared__ float wloc[4];
  if (tid < 4) { rloc[tid] = rowmap[t * 4 + tid]; wloc[tid] = tw[t * 4 + tid]; }
  __syncthreads();
  int c = tid * 4;   // 256 threads x 4 cols = 1024
  float4 a = {0.f, 0.f, 0.f, 0.f};
#pragma unroll
  for (int k = 0; k < 4; ++k) {
    ushort4 v = *(const ushort4*)&ybuf[(size_t)rloc[k] * H_DIM + c];
    float w = wloc[k];
    a.x += w * bf2f(v.x); a.y += w * bf2f(v.y);
    a.z += w * bf2f(v.z); a.w += w * bf2f(v.w);
  }
  *(float4*)&out[(size_t)t * H_DIM + c] = a;
}

// ---------------------------------------------------------------- launch
extern "C" void kernel_launch(void* const* d_in, const int* in_sizes, int n_in,
                              void* d_out, int out_size, void* d_ws, size_t ws_size,
                              hipStream_t stream) {
  (void)in_sizes; (void)n_in; (void)out_size; (void)ws_size;
  const float* x  = (const float*)d_in[0];
  const float* rw = (const float*)d_in[1];
  const float* rb = (const float*)d_in[2];
  const float* wg = (const float*)d_in[3];
  const float* wu = (const float*)d_in[4];
  const float* wd = (const float*)d_in[5];
  float* out = (float*)d_out;

  char* base = (char*)d_ws;
  size_t o = 0;
  auto alloc = [&](size_t b) -> void* {
    void* p = base + o;
    o += (b + 255) & ~(size_t)255;
    return p;
  };
  unsigned short* xbf   = (unsigned short*)alloc((size_t)T_TOK * H_DIM * 2);
  unsigned short* hbuf  = (unsigned short*)alloc((size_t)T_TOK * TOPK * I_DIM * 2);
  unsigned short* ybuf  = (unsigned short*)alloc((size_t)T_TOK * TOPK * H_DIM * 2);
  float* logits = (float*)alloc((size_t)T_TOK * E_EXP * 4);
  int*   tidx   = (int*)alloc((size_t)T_TOK * TOPK * 4);
  float* tw     = (float*)alloc((size_t)T_TOK * TOPK * 4);
  int*   rowmap = (int*)alloc((size_t)T_TOK * TOPK * 4);
  int*   rowtok = (int*)alloc((size_t)T_TOK * TOPK * 4);
  int*   counts = (int*)alloc(256);
  int*   offb   = (int*)alloc(256);
  int*   toffb  = (int*)alloc(256);

  logits_kernel<<<T_TOK / 4, 256, 0, stream>>>(x, rw, logits, xbf);
  select_kernel<<<T_TOK / 256, 256, 0, stream>>>(logits, rb, tidx, tw);
  count_kernel<<<E_EXP, 256, 0, stream>>>(tidx, counts);
  prefix_kernel<<<1, 64, 0, stream>>>(counts, offb, toffb);
  scatter_kernel<<<E_EXP, 256, 0, stream>>>(tidx, offb, rowmap, rowtok);

  gateup_kernel<<<8 * NTILEMAX, 256, 0, stream>>>(xbf, wg, wu, rowtok, offb, toffb, hbuf);
  down_kernel<<<8 * NTILEMAX, 256, 0, stream>>>(hbuf, wd, offb, toffb, ybuf);
  combine_kernel<<<T_TOK, 256, 0, stream>>>(ybuf, rowmap, tw, out);
}

// Round 11
// 151.629 us; speedup vs baseline: 1.1593x; 1.0314x over previous
//
#include <hip/hip_runtime.h>
#include <stdint.h>

// Problem constants (B=2, S=2048 -> T=4096 tokens)
#define T_TOK   4096
#define H_DIM   1024
#define I_DIM   512
#define E_EXP   16
#define TOPK    4
#define NTILEMAX 144   // >= max total 128-row M-tiles (<=143); 8*144=1152 blocks

typedef __attribute__((ext_vector_type(8))) short bf16x8;   // 8 bf16 = 4 VGPR
typedef __attribute__((ext_vector_type(4))) float f32x4;    // MFMA 16x16 acc

__device__ __forceinline__ unsigned short f2bf(float f) {
  unsigned u = __float_as_uint(f);
  u = u + 0x7fffu + ((u >> 16) & 1u);          // RNE
  return (unsigned short)(u >> 16);
}
__device__ __forceinline__ float bf2f(unsigned short s) {
  return __uint_as_float(((unsigned)s) << 16);
}

// pack 2 fp32 -> 2 bf16 in one dword (RNE), gfx950 HW instruction
__device__ __forceinline__ unsigned cvtpk(float lo, float hi) {
  unsigned r;
  asm("v_cvt_pk_bf16_f32 %0, %1, %2" : "=v"(r) : "v"(lo), "v"(hi));
  return r;
}

__device__ __forceinline__ void gload_lds16(const void* g, void* l) {
  __builtin_amdgcn_global_load_lds(
      (const __attribute__((address_space(1))) unsigned int*)g,
      (__attribute__((address_space(3))) unsigned int*)l, 16, 0, 0);
}

// ---------------------------------------------------------------- router 1/4
// Wave per token: router logits AND bf16 conversion of the x row (fused).
__global__ __launch_bounds__(256) void logits_kernel(
    const float* __restrict__ x, const float* __restrict__ rw,
    float* __restrict__ logits, unsigned short* __restrict__ xb) {
  const int t = blockIdx.x * 4 + (threadIdx.x >> 6);
  const int lane = threadIdx.x & 63;
  const float* xr = x + (size_t)t * H_DIM;

  float4 xv[4];
#pragma unroll
  for (int i = 0; i < 4; ++i) xv[i] = ((const float4*)xr)[i * 64 + lane];

  unsigned short* xrow = xb + (size_t)t * H_DIM;
#pragma unroll
  for (int i = 0; i < 4; ++i) {
    ushort4 o;
    o.x = f2bf(xv[i].x); o.y = f2bf(xv[i].y);
    o.z = f2bf(xv[i].z); o.w = f2bf(xv[i].w);
    ((ushort4*)xrow)[i * 64 + lane] = o;
  }

#pragma unroll
  for (int g = 0; g < 4; ++g) {
    float acc[4] = {0.f, 0.f, 0.f, 0.f};
#pragma unroll
    for (int e4 = 0; e4 < 4; ++e4) {
      const float* wrow = rw + (size_t)(g * 4 + e4) * H_DIM;
#pragma unroll
      for (int i = 0; i < 4; ++i) {
        float4 wv = ((const float4*)wrow)[i * 64 + lane];
        acc[e4] = fmaf(xv[i].x, wv.x, acc[e4]);
        acc[e4] = fmaf(xv[i].y, wv.y, acc[e4]);
        acc[e4] = fmaf(xv[i].z, wv.z, acc[e4]);
        acc[e4] = fmaf(xv[i].w, wv.w, acc[e4]);
      }
    }
#pragma unroll
    for (int e4 = 0; e4 < 4; ++e4)
#pragma unroll
      for (int off = 32; off > 0; off >>= 1) acc[e4] += __shfl_down(acc[e4], off, 64);
    if (lane == 0)
      ((float4*)(logits + (size_t)t * E_EXP))[g] =
          make_float4(acc[0], acc[1], acc[2], acc[3]);
  }
}

// ---------------------------------------------------------------- router 2/4
__global__ __launch_bounds__(256) void select_kernel(
    const float* __restrict__ logits, const float* __restrict__ rb,
    int* __restrict__ tidx, float* __restrict__ tw) {
  const int t = blockIdx.x * 256 + threadIdx.x;

  float sc[E_EXP], sch[E_EXP];
#pragma unroll
  for (int e = 0; e < E_EXP; ++e) {
    sc[e] = 1.f / (1.f + expf(-logits[(size_t)t * E_EXP + e]));
    sch[e] = sc[e] + rb[e];
  }

  float gsum[4];
#pragma unroll
  for (int g = 0; g < 4; ++g) {
    float m1 = -3e38f, m2 = -3e38f;
#pragma unroll
    for (int j = 0; j < 4; ++j) {
      float v = sch[g * 4 + j];
      if (v > m1) { m2 = m1; m1 = v; } else if (v > m2) { m2 = v; }
    }
    gsum[g] = m1 + m2;
  }
  int g1 = 0;
  for (int g = 1; g < 4; ++g) if (gsum[g] > gsum[g1]) g1 = g;
  int g2 = -1;
  for (int g = 0; g < 4; ++g)
    if (g != g1 && (g2 < 0 || gsum[g] > gsum[g2])) g2 = g;

  float cand[E_EXP];
#pragma unroll
  for (int e = 0; e < E_EXP; ++e)
    cand[e] = ((e >> 2) == g1 || (e >> 2) == g2) ? sch[e] : -1e9f;

  int idx[TOPK]; float wv[TOPK]; float wsum = 0.f;
#pragma unroll
  for (int k = 0; k < TOPK; ++k) {
    int bi = 0; float bv = cand[0];
#pragma unroll
    for (int e = 1; e < E_EXP; ++e) if (cand[e] > bv) { bv = cand[e]; bi = e; }
    idx[k] = bi; cand[bi] = -3e38f;
    wv[k] = sc[bi];
    wsum += wv[k];
  }
  float scale = 2.5f / (wsum + 1e-20f);
#pragma unroll
  for (int k = 0; k < TOPK; ++k) {
    tidx[t * 4 + k] = idx[k];
    tw[t * 4 + k] = wv[k] * scale;
  }
}

// ---------------------------------------------------------------- router 3/4
__global__ __launch_bounds__(256) void count_kernel(
    const int* __restrict__ tidx, int* __restrict__ counts) {
  const int e = blockIdx.x, tid = threadIdx.x;
  const int lane = tid & 63, wv = tid >> 6;
  int local = 0;
  for (int i = tid; i < T_TOK * TOPK; i += 256) local += (tidx[i] == e);
#pragma unroll
  for (int off = 32; off > 0; off >>= 1) local += __shfl_down(local, off, 64);
  __shared__ int ws[4];
  if (lane == 0) ws[wv] = local;
  __syncthreads();
  if (tid == 0) counts[e] = ws[0] + ws[1] + ws[2] + ws[3];
}

// prefix over rows AND over 128-row M-tiles (compact dispatch table)
__global__ void prefix_kernel(const int* __restrict__ counts,
                              int* __restrict__ off, int* __restrict__ toff) {
  if (threadIdx.x == 0) {
    int a = 0, tt = 0;
    for (int e = 0; e < E_EXP; ++e) {
      off[e] = a; toff[e] = tt;
      a += counts[e];
      tt += (counts[e] + 127) >> 7;
    }
    off[E_EXP] = a;                 // == 4*T
    toff[E_EXP] = tt;               // total M-tiles (<= 143)
  }
}

// ---------------------------------------------------------------- router 4/4
__global__ __launch_bounds__(256) void scatter_kernel(
    const int* __restrict__ tidx, const int* __restrict__ off,
    int* __restrict__ rowmap, int* __restrict__ rowtok) {
  const int e = blockIdx.x, tid = threadIdx.x;
  const int lane = tid & 63, wv = tid >> 6;
  __shared__ int wsum[4];
  __shared__ int srun;
  if (tid == 0) srun = 0;
  __syncthreads();
  const int base = off[e];
  for (int c = 0; c < T_TOK * TOPK / 256; ++c) {
    const int i = c * 256 + tid;
    const bool f = (tidx[i] == e);
    unsigned long long m = __ballot(f);
    int wpre = __popcll(m & ((1ull << lane) - 1ull));
    if (lane == 63) wsum[wv] = wpre + (f ? 1 : 0);
    __syncthreads();
    const int run = srun;
    int pre = 0, tot = 0;
#pragma unroll
    for (int w = 0; w < 4; ++w) {
      int v = wsum[w];
      if (w < wv) pre += v;
      tot += v;
    }
    if (f) {
      const int pos = base + run + pre + wpre;
      rowmap[i] = pos;
      rowtok[pos] = i >> 2;
    }
    __syncthreads();
    if (tid == 0) srun = run + tot;
  }
}

// decode compact tile id -> expert (monotone table walk, branchless)
__device__ __forceinline__ int find_expert(const int* __restrict__ toff, int tile) {
  int e = 0;
#pragma unroll
  for (int q = 1; q <= E_EXP; ++q) e += (toff[q] <= tile);
  return e;
}

// ---------------------------------------------------------------- gate+up GEMM
// Fused fp32 weight conversion with RACE-SAFE async split:
//   top:   stage A (gload_lds) + cvt/ds_write B(kt) from regs
//   barrier1 = __syncthreads (exact drain: only A + ds_writes in flight)
//   issue B(kt+1) loads  -> they fly across barrier2 (reg-dest only, no LDS hazard)
//   MFMA phase
//   barrier2 = raw s_barrier bracketed by sched_barrier(0)
__global__ __launch_bounds__(256, 3) void gateup_kernel(
    const unsigned short* __restrict__ xbf,   // [T,H] bf16
    const float* __restrict__ wgf,            // [E,I,H] fp32
    const float* __restrict__ wuf,            // [E,I,H] fp32
    const int* __restrict__ rowtok, const int* __restrict__ off,
    const int* __restrict__ toff,
    unsigned short* __restrict__ hbuf) {      // [4T,I]
  const int bid = (int)blockIdx.x;
  const int work = (bid & 7) * NTILEMAX + (bid >> 3);
  const int tile = work >> 3, tn = work & 7;
  if (tile >= toff[E_EXP]) return;
  const int e = find_expert(toff, tile);
  const int tm = tile - toff[e];
  const int seg0 = off[e];
  const int nrows = off[e + 1] - seg0;

  __shared__ __align__(16) unsigned short As[128 * 64];  // 16KB
  __shared__ __align__(16) unsigned short Gs[64 * 64];   // 8KB
  __shared__ __align__(16) unsigned short Us[64 * 64];   // 8KB
  __shared__ int ids[128];

  const int tid = threadIdx.x;
  if (tid < 128) {
    int r = tm * 128 + tid;
    ids[tid] = rowtok[seg0 + (r < nrows ? r : 0)];       // clamp: safe read
  }
  __syncthreads();

  const int col8 = tid & 7;        // 16B chunk within a 64-elem row
  const int r0 = tid >> 3;         // row base within 32-row stripe
  const int csrc = (col8 ^ (r0 & 7)) * 8;  // pre-swizzled source column (A)
  const int bcol = col8 * 8;               // linear source column (B, fp32)
  const int bdst = (col8 ^ (r0 & 7)) * 8;  // swizzled LDS dest chunk (B)
  int tokA[4];
#pragma unroll
  for (int j = 0; j < 4; ++j) tokA[j] = ids[j * 32 + r0];

  const float* wg = wgf + (size_t)e * I_DIM * H_DIM + (size_t)(tn * 64) * H_DIM;
  const float* wu = wuf + (size_t)e * I_DIM * H_DIM + (size_t)(tn * 64) * H_DIM;

  f32x4 accg[4][2], accu[4][2];
#pragma unroll
  for (int m = 0; m < 4; ++m)
#pragma unroll
    for (int n = 0; n < 2; ++n) { accg[m][n] = (f32x4)0.f; accu[m][n] = (f32x4)0.f; }

  const int lane = tid & 63, wid = tid >> 6;
  const int wr = wid >> 1, wc = wid & 1;
  const int frow = lane & 15, fr7 = frow & 7;
  const int kc = lane >> 4;        // base chunk (0..3) within K=64 row

  const int NT = H_DIM / 64;       // 16
  float4 Bg[2][2], Bu[2][2];       // in-flight B regs (8 float4 = 32 VGPR)

  auto loadB = [&](int kt) {
#pragma unroll
    for (int j = 0; j < 2; ++j) {
      const float* gs = wg + (size_t)(j * 32 + r0) * H_DIM + kt * 64 + bcol;
      const float* us = wu + (size_t)(j * 32 + r0) * H_DIM + kt * 64 + bcol;
      Bg[j][0] = ((const float4*)gs)[0]; Bg[j][1] = ((const float4*)gs)[1];
      Bu[j][0] = ((const float4*)us)[0]; Bu[j][1] = ((const float4*)us)[1];
    }
  };

  loadB(0);                        // prologue
  for (int kt = 0; kt < NT; ++kt) {
    const int kbA = kt * 64 + csrc;
    // stage A: async global->LDS (4 ops)
#pragma unroll
    for (int j = 0; j < 4; ++j)
      gload_lds16(xbf + ((size_t)tokA[j] * H_DIM + kbA), (char*)As + (j * 256 + tid) * 16);
    // stage B: convert regs (compiler drains the B loads here), write swizzled
#pragma unroll
    for (int j = 0; j < 2; ++j) {
      const int row = j * 32 + r0;
      uint4 gw, uw;
      gw.x = cvtpk(Bg[j][0].x, Bg[j][0].y); gw.y = cvtpk(Bg[j][0].z, Bg[j][0].w);
      gw.z = cvtpk(Bg[j][1].x, Bg[j][1].y); gw.w = cvtpk(Bg[j][1].z, Bg[j][1].w);
      uw.x = cvtpk(Bu[j][0].x, Bu[j][0].y); uw.y = cvtpk(Bu[j][0].z, Bu[j][0].w);
      uw.z = cvtpk(Bu[j][1].x, Bu[j][1].y); uw.w = cvtpk(Bu[j][1].z, Bu[j][1].w);
      *(uint4*)&Gs[row * 64 + bdst] = gw;
      *(uint4*)&Us[row * 64 + bdst] = uw;
    }
    // barrier1: full drain (only A gloads + ds_writes are in flight -> exact)
    __syncthreads();
    // issue next-tile B loads now: reg-dest only, they legally cross barrier2
    if (kt + 1 < NT) loadB(kt + 1);
    __builtin_amdgcn_sched_barrier(0);   // pin loads above the MFMA cluster
#pragma unroll
    for (int kk = 0; kk < 2; ++kk) {
      const int swz = ((kk * 4 + kc) ^ fr7) * 8;   // swizzled elem offset
      bf16x8 af[4], bg[2], bu[2];
#pragma unroll
      for (int m = 0; m < 4; ++m)
        af[m] = *(const bf16x8*)&As[(wr * 64 + m * 16 + frow) * 64 + swz];
#pragma unroll
      for (int n = 0; n < 2; ++n) {
        bg[n] = *(const bf16x8*)&Gs[(wc * 32 + n * 16 + frow) * 64 + swz];
        bu[n] = *(const bf16x8*)&Us[(wc * 32 + n * 16 + frow) * 64 + swz];
      }
#pragma unroll
      for (int m = 0; m < 4; ++m)
#pragma unroll
        for (int n = 0; n < 2; ++n) {
          accg[m][n] = __builtin_amdgcn_mfma_f32_16x16x32_bf16(af[m], bg[n], accg[m][n], 0, 0, 0);
          accu[m][n] = __builtin_amdgcn_mfma_f32_16x16x32_bf16(af[m], bu[n], accu[m][n], 0, 0, 0);
        }
    }
    __builtin_amdgcn_sched_barrier(0);   // nothing sinks below barrier2
    __builtin_amdgcn_s_barrier();        // barrier2: B loads stay in flight
    __builtin_amdgcn_sched_barrier(0);   // next tile's LDS writes can't hoist
  }

  // epilogue: h = silu(g)*u  (C/D layout: col=lane&15, row=(lane>>4)*4+j)
  const int lr = (lane >> 4) * 4, lc = lane & 15;
#pragma unroll
  for (int m = 0; m < 4; ++m) {
#pragma unroll
    for (int j = 0; j < 4; ++j) {
      int r = tm * 128 + wr * 64 + m * 16 + lr + j;
      if (r < nrows) {
        size_t rowoff = (size_t)(seg0 + r) * I_DIM;
#pragma unroll
        for (int n = 0; n < 2; ++n) {
          float g = accg[m][n][j];
          float u = accu[m][n][j];
          float hv = g / (1.f + __expf(-g)) * u;
          hbuf[rowoff + tn * 64 + wc * 32 + n * 16 + lc] = f2bf(hv);
        }
      }
    }
  }
}

// ---------------------------------------------------------------- down GEMM
// Tile 128x128, BK=64 over I, 3/CU. Same race-safe async split for fp32 B.
__global__ __launch_bounds__(256, 3) void down_kernel(
    const unsigned short* __restrict__ hbuf,  // [4T,I] bf16
    const float* __restrict__ wdf,            // [E,H,I] fp32
    const int* __restrict__ off, const int* __restrict__ toff,
    unsigned short* __restrict__ ybuf) {      // [4T,H]
  const int bid = (int)blockIdx.x;
  const int work = (bid & 7) * NTILEMAX + (bid >> 3);
  const int tile = work >> 3, tn = work & 7;
  if (tile >= toff[E_EXP]) return;
  const int e = find_expert(toff, tile);
  const int tm = tile - toff[e];
  const int seg0 = off[e];
  const int nrows = off[e + 1] - seg0;

  __shared__ __align__(16) unsigned short As[128 * 64];  // 16KB
  __shared__ __align__(16) unsigned short Bs[128 * 64];  // 16KB

  const int tid = threadIdx.x;
  const int col8 = tid & 7;
  const int r0 = tid >> 3;
  const int csrc = (col8 ^ (r0 & 7)) * 8;
  const int bcol = col8 * 8;
  const int bdst = (col8 ^ (r0 & 7)) * 8;
  int rowA[4];
#pragma unroll
  for (int j = 0; j < 4; ++j) {
    int r = tm * 128 + j * 32 + r0;
    rowA[j] = seg0 + (r < nrows ? r : nrows - 1);
  }
  const float* wd = wdf + (size_t)e * H_DIM * I_DIM + (size_t)(tn * 128) * I_DIM;

  f32x4 acc[4][4];
#pragma unroll
  for (int m = 0; m < 4; ++m)
#pragma unroll
    for (int n = 0; n < 4; ++n) acc[m][n] = (f32x4)0.f;

  const int lane = tid & 63, wid = tid >> 6;
  const int wr = wid >> 1, wc = wid & 1;
  const int frow = lane & 15, fr7 = frow & 7;
  const int kc = lane >> 4;

  const int NT = I_DIM / 64;       // 8
  float4 Bd[4][2];                 // in-flight B regs (8 float4)

  auto loadB = [&](int kt) {
#pragma unroll
    for (int j = 0; j < 4; ++j) {
      const float* ds = wd + (size_t)(j * 32 + r0) * I_DIM + kt * 64 + bcol;
      Bd[j][0] = ((const float4*)ds)[0]; Bd[j][1] = ((const float4*)ds)[1];
    }
  };

  loadB(0);
  for (int kt = 0; kt < NT; ++kt) {
    const int kbA = kt * 64 + csrc;
#pragma unroll
    for (int j = 0; j < 4; ++j)
      gload_lds16(hbuf + ((size_t)rowA[j] * I_DIM + kbA), (char*)As + (j * 256 + tid) * 16);
#pragma unroll
    for (int j = 0; j < 4; ++j) {
      const int row = j * 32 + r0;
      uint4 w;
      w.x = cvtpk(Bd[j][0].x, Bd[j][0].y); w.y = cvtpk(Bd[j][0].z, Bd[j][0].w);
      w.z = cvtpk(Bd[j][1].x, Bd[j][1].y); w.w = cvtpk(Bd[j][1].z, Bd[j][1].w);
      *(uint4*)&Bs[row * 64 + bdst] = w;
    }
    __syncthreads();                     // barrier1: exact drain
    if (kt + 1 < NT) loadB(kt + 1);      // reg-dest loads cross barrier2
    __builtin_amdgcn_sched_barrier(0);
#pragma unroll
    for (int kk = 0; kk < 2; ++kk) {
      const int swz = ((kk * 4 + kc) ^ fr7) * 8;
      bf16x8 af[4], bw[4];
#pragma unroll
      for (int m = 0; m < 4; ++m)
        af[m] = *(const bf16x8*)&As[(wr * 64 + m * 16 + frow) * 64 + swz];
#pragma unroll
      for (int n = 0; n < 4; ++n)
        bw[n] = *(const bf16x8*)&Bs[(wc * 64 + n * 16 + frow) * 64 + swz];
#pragma unroll
      for (int m = 0; m < 4; ++m)
#pragma unroll
        for (int n = 0; n < 4; ++n)
          acc[m][n] = __builtin_amdgcn_mfma_f32_16x16x32_bf16(af[m], bw[n], acc[m][n], 0, 0, 0);
    }
    __builtin_amdgcn_sched_barrier(0);
    __builtin_amdgcn_s_barrier();        // barrier2
    __builtin_amdgcn_sched_barrier(0);
  }

  const int lr = (lane >> 4) * 4, lc = lane & 15;
#pragma unroll
  for (int m = 0; m < 4; ++m) {
#pragma unroll
    for (int j = 0; j < 4; ++j) {
      int r = tm * 128 + wr * 64 + m * 16 + lr + j;
      if (r < nrows) {
        size_t rowoff = (size_t)(seg0 + r) * H_DIM;
#pragma unroll
        for (int n = 0; n < 4; ++n)
          ybuf[rowoff + tn * 128 + wc * 64 + n * 16 + lc] = f2bf(acc[m][n][j]);
      }
    }
  }
}

// ---------------------------------------------------------------- combine
__global__ __launch_bounds__(256) void combine_kernel(
    const unsigned short* __restrict__ ybuf, const int* __restrict__ rowmap,
    const float* __restrict__ tw, float* __restrict__ out) {
  int t = blockIdx.x, tid = threadIdx.x;
  __shared__ int rloc[4];
  __shared__ float wloc[4];
  if (tid < 4) { rloc[tid] = rowmap[t * 4 + tid]; wloc[tid] = tw[t * 4 + tid]; }
  __syncthreads();
  int c = tid * 4;   // 256 threads x 4 cols = 1024
  float4 a = {0.f, 0.f, 0.f, 0.f};
#pragma unroll
  for (int k = 0; k < 4; ++k) {
    ushort4 v = *(const ushort4*)&ybuf[(size_t)rloc[k] * H_DIM + c];
    float w = wloc[k];
    a.x += w * bf2f(v.x); a.y += w * bf2f(v.y);
    a.z += w * bf2f(v.z); a.w += w * bf2f(v.w);
  }
  *(float4*)&out[(size_t)t * H_DIM + c] = a;
}

// ---------------------------------------------------------------- launch
extern "C" void kernel_launch(void* const* d_in, const int* in_sizes, int n_in,
                              void* d_out, int out_size, void* d_ws, size_t ws_size,
                              hipStream_t stream) {
  (void)in_sizes; (void)n_in; (void)out_size; (void)ws_size;
  const float* x  = (const float*)d_in[0];
  const float* rw = (const float*)d_in[1];
  const float* rb = (const float*)d_in[2];
  const float* wg = (const float*)d_in[3];
  const float* wu = (const float*)d_in[4];
  const float* wd = (const float*)d_in[5];
  float* out = (float*)d_out;

  char* base = (char*)d_ws;
  size_t o = 0;
  auto alloc = [&](size_t b) -> void* {
    void* p = base + o;
    o += (b + 255) & ~(size_t)255;
    return p;
  };
  unsigned short* xbf   = (unsigned short*)alloc((size_t)T_TOK * H_DIM * 2);
  unsigned short* hbuf  = (unsigned short*)alloc((size_t)T_TOK * TOPK * I_DIM * 2);
  unsigned short* ybuf  = (unsigned short*)alloc((size_t)T_TOK * TOPK * H_DIM * 2);
  float* logits = (float*)alloc((size_t)T_TOK * E_EXP * 4);
  int*   tidx   = (int*)alloc((size_t)T_TOK * TOPK * 4);
  float* tw     = (float*)alloc((size_t)T_TOK * TOPK * 4);
  int*   rowmap = (int*)alloc((size_t)T_TOK * TOPK * 4);
  int*   rowtok = (int*)alloc((size_t)T_TOK * TOPK * 4);
  int*   counts = (int*)alloc(256);
  int*   offb   = (int*)alloc(256);
  int*   toffb  = (int*)alloc(256);

  logits_kernel<<<T_TOK / 4, 256, 0, stream>>>(x, rw, logits, xbf);
  select_kernel<<<T_TOK / 256, 256, 0, stream>>>(logits, rb, tidx, tw);
  count_kernel<<<E_EXP, 256, 0, stream>>>(tidx, counts);
  prefix_kernel<<<1, 64, 0, stream>>>(counts, offb, toffb);
  scatter_kernel<<<E_EXP, 256, 0, stream>>>(tidx, offb, rowmap, rowtok);

  gateup_kernel<<<8 * NTILEMAX, 256, 0, stream>>>(xbf, wg, wu, rowtok, offb, toffb, hbuf);
  down_kernel<<<8 * NTILEMAX, 256, 0, stream>>>(hbuf, wd, offb, toffb, ybuf);
  combine_kernel<<<T_TOK, 256, 0, stream>>>(ybuf, rowmap, tw, out);
}